// Round 2
// baseline (302.025 us; speedup 1.0000x reference)
//
#include <hip/hip_runtime.h>
#include <math.h>

// QFCModel: avgpool(6x6) -> linear(16->4) -> 4-qubit circuit -> <Z> -> batchnorm
//
// |psi> = U_var * |enc(f)>, U_var fixed 16x16 complex (from vparams).
// enc[j] = r_j * (-i)^popcount(j), r_j real product of cos/sin half-angles.
// Fold phase into U columns => y_i = sum_j U'[i][j] * r_j  (real multiplier).
// <Z_w> = Walsh coefficient m=1<<(3-w) of q_i = |y_i|^2 (16-lane shfl butterfly).
//
// R5: persistent double-buffered pipeline (T3/T4 "minimum 2-phase"):
// 512 blocks (2/CU, LDS 2x36.9KB), 8 image-sets each. Per iteration:
//   barrier1 (prev compute done -> nxt buf free)
//   issue 9 global_load_lds for set t+1 into buf^1   (counted, never drained)
//   s_waitcnt vmcnt(9)  (cur set's loads retired; 9 newest stay in flight)
//   barrier2; compute cur buf
// Loads stay in flight across barriers -> mem pipe never idles during the
// ~800cy compute tail. Source addrs precomputed once (9 u32 offsets/thread,
// uniform stride advance). acc: per-block owned slot (plain store) -> no
// memset dispatch, no double atomics. 2 dispatches total.

#define IMG_PER_SET 16
#define IMG_F 784            // floats per image (28*28)
#define IMG_F4 196           // float4s per image
#define IMG_BYTES 3136
#define ROW_F4 6             // float4s per staged row (cols 0..23)
#define STG_F4 144           // float4s staged per image (24 rows * 6)
#define STG_F 576            // floats staged per image (24*24)
#define SET_F4 (IMG_PER_SET * STG_F4)   // 2304 = 9*256 exactly
#define SET_F  (IMG_PER_SET * STG_F)    // 9216 floats = 36864 B
#define NBLOCKS 512

#define GLOAD16(g, l) __builtin_amdgcn_global_load_lds( \
    (const __attribute__((address_space(1))) void*)(g), \
    (__attribute__((address_space(3))) void*)(l), 16, 0, 0)

__global__ __launch_bounds__(256, 2) void qfc_main(
    const float* __restrict__ x,
    const float* __restrict__ W,
    const float* __restrict__ bias,
    const float* __restrict__ vparams,
    float* __restrict__ out,
    double* __restrict__ acc,   // [nblk][8]: 4 sums, 4 sumsq (per-block owned)
    int B, int nsets_tot, int nblk, int nsets_blk)
{
    __shared__ float  lds_img[2 * SET_F];               // 73728 B (double buf)
    __shared__ float2 Uc[256];                          // 2048 B
    __shared__ float  bsum[4], bsq[4];

    const int t   = threadIdx.x;
    const int blk = blockIdx.x;
    const int wb  = t & 192;                            // wave base (float4)
    const unsigned ADV = (unsigned)nblk * (unsigned)(IMG_PER_SET * IMG_BYTES);

    if (t < 4) { bsum[t] = 0.f; bsq[t] = 0.f; }

    // ---- per-thread source byte offsets for set0 = blk (9 loads) ----
    unsigned off[9];
    #pragma unroll
    for (int k = 0; k < 9; ++k) {
        int q    = t + k * 256;
        int g    = q / STG_F4;
        int r4   = q - g * STG_F4;
        int row  = r4 / ROW_F4;
        int col4 = r4 - row * ROW_F4;
        long img = (long)blk * IMG_PER_SET + g;
        if (img >= B) img = B - 1;                      // clamp (partial tail)
        off[k] = (unsigned)(img * IMG_BYTES + row * 112 + col4 * 16);
    }

    // ---- prologue: issue DMA for set0 into buf0 ----
    {
        float4* lds4 = (float4*)lds_img;
        #pragma unroll
        for (int k = 0; k < 9; ++k)
            GLOAD16((const char*)x + off[k], lds4 + k * 256 + wb);
    }

    // ---- U'-build (overlaps set0 DMA). t -> column j = t>>4, row i = t&15 ----
    {
        const int j = t >> 4, i = t & 15;
        float ux = (i == j) ? 1.f : 0.f, uy = 0.f;
        for (int l = 0; l < 3; ++l) {
            for (int w = 0; w < 4; ++w) {
                const float* vp = vparams + (l * 4 + w) * 3;
                const int m = 8 >> w;       // wire w = state bit (3-w)
                float s, c;
                // RX: [c, -i s; -i s, c]
                __sincosf(0.5f * vp[0], &s, &c);
                {
                    float ox = __shfl_xor(ux, m);
                    float oy = __shfl_xor(uy, m);
                    float nx = c * ux + s * oy;
                    float ny = c * uy - s * ox;
                    ux = nx; uy = ny;
                }
                // RY: [c, -s; s, c]
                __sincosf(0.5f * vp[1], &s, &c);
                {
                    float ox = __shfl_xor(ux, m);
                    float oy = __shfl_xor(uy, m);
                    float sg = (i & m) ? s : -s;
                    ux = c * ux + sg * ox;
                    uy = c * uy + sg * oy;
                }
                // RZ: diag(e^{-it/2}, e^{it/2})
                __sincosf(0.5f * vp[2], &s, &c);
                {
                    float sg = (i & m) ? s : -s;
                    float nx = ux * c - sg * uy;
                    float ny = uy * c + sg * ux;
                    ux = nx; uy = ny;
                }
            }
            // CNOT chain: control bit (3-w), target bit (2-w)
            for (int w = 0; w < 3; ++w) {
                int mc = 8 >> w, mt = 4 >> w;
                float ox = __shfl_xor(ux, mt);
                float oy = __shfl_xor(uy, mt);
                if (i & mc) { ux = ox; uy = oy; }
            }
        }
        int pc = __popc(j) & 3;             // fold column phase (-i)^popcount(j)
        float px, py;
        if (pc == 0)      { px =  ux; py =  uy; }
        else if (pc == 1) { px =  uy; py = -ux; }
        else if (pc == 2) { px = -ux; py = -uy; }
        else              { px = -uy; py =  ux; }
        Uc[t] = make_float2(px, py);        // Uc[j*16+i] = U'[j][i]
    }
    // retire LDS writes (Uc, bsum zero) before cross-wave use
    asm volatile("s_waitcnt lgkmcnt(0)" ::: "memory");

    // ---- main pipeline ----
    for (int it = 0; it < nsets_blk; ++it) {
        const int set = blk + it * nblk;            // strided set ownership
        const bool adv = (set + nblk) < nsets_tot;  // block-uniform

        // barrier1: everyone done computing set-1 -> buf^1 is free
        __builtin_amdgcn_s_barrier();

        if (adv) {
            float4* nbuf = (float4*)(lds_img + ((it + 1) & 1) * SET_F);
            #pragma unroll
            for (int k = 0; k < 9; ++k) {
                off[k] += ADV;
                GLOAD16((const char*)x + off[k], nbuf + k * 256 + wb);
            }
            // cur set's 9 loads (issued last iter) retired; 9 newest in flight
            asm volatile("s_waitcnt vmcnt(9)" ::: "memory");
        } else {
            asm volatile("s_waitcnt vmcnt(0)" ::: "memory");
        }

        // barrier2: all waves' cur-set data is in LDS
        __builtin_amdgcn_s_barrier();

        if (set < nsets_tot) {
            const float* cbuf = lds_img + (it & 1) * SET_F;

            // ---- pooling: thread t -> image g = t>>4, cell = t&15 ----
            float pv;
            {
                const int g = t >> 4, cell = t & 15;
                const int ci = cell >> 2, cj = cell & 3;
                const float* base = cbuf + g * STG_F + ci * 6 * 24 + cj * 6;
                float sum = 0.f;
                #pragma unroll
                for (int r = 0; r < 6; ++r) {
                    const float2* p2 = (const float2*)(base + r * 24);
                    float2 a = p2[0], b2 = p2[1], c2 = p2[2];
                    sum += a.x + a.y + b2.x + b2.y + c2.x + c2.y;
                }
                pv = sum * (1.0f / 36.0f);
            }
            // pooled value for (g, cell=k) lives in wave lane (t&48)|k

            // ---- per-sample circuit: thread t -> image g, row i ----
            {
                const int g = t >> 4, i = t & 15;
                float f0 = bias[0], f1 = bias[1], f2 = bias[2], f3 = bias[3];
                #pragma unroll
                for (int k = 0; k < 16; ++k) {
                    float p = __shfl(pv, (t & 48) | k, 64);
                    f0 += p * W[k * 4 + 0];
                    f1 += p * W[k * 4 + 1];
                    f2 += p * W[k * 4 + 2];
                    f3 += p * W[k * 4 + 3];
                }
                float c0, s0, c1, s1, c2, s2, c3, s3;
                __sincosf(0.5f * f0, &s0, &c0);
                __sincosf(0.5f * f1, &s1, &c1);
                __sincosf(0.5f * f2, &s2, &c2);
                __sincosf(0.5f * f3, &s3, &c3);
                // r_j = AB[j>>2] * CD[j&3]; bit3=wire0 ... bit0=wire3
                float AB[4] = { c0 * c1, c0 * s1, s0 * c1, s0 * s1 };
                float CD[4] = { c2 * c3, c2 * s3, s2 * c3, s2 * s3 };
                float yx = 0.f, yy = 0.f;
                #pragma unroll
                for (int j = 0; j < 16; ++j) {
                    float r = AB[j >> 2] * CD[j & 3];
                    float2 u = Uc[j * 16 + i];
                    yx += u.x * r;
                    yy += u.y * r;
                }
                float q = yx * yx + yy * yy;
                // 16-lane Walsh-Hadamard butterfly
                #pragma unroll
                for (int d = 1; d <= 8; d <<= 1) {
                    float o = __shfl_xor(q, d);
                    q = (i & d) ? (o - q) : (o + q);
                }
                int img = set * IMG_PER_SET + g;
                if ((i == 1 || i == 2 || i == 4 || i == 8) && img < B) {
                    int w = (i == 8) ? 0 : (i == 4) ? 1 : (i == 2) ? 2 : 3;
                    out[img * 4 + w] = q;       // raw <Z_w>, normalized later
                    atomicAdd(&bsum[w], q);
                    atomicAdd(&bsq[w],  q * q);
                }
            }
        }
    }

    __syncthreads();    // all LDS atomics retired
    if (t < 8) {
        float v = (t < 4) ? bsum[t] : bsq[t - 4];
        acc[blk * 8 + t] = (double)v;           // owned slot, no zeroing needed
    }
}

__global__ __launch_bounds__(256) void qfc_bn(
    float* __restrict__ out,
    const double* __restrict__ acc,
    const float* __restrict__ gamma,
    const float* __restrict__ beta,
    int B, int nblk)
{
    __shared__ double red[64];
    __shared__ double tot_s[8];
    __shared__ float  mu_s[4], sc_s[4], bt_s[4];
    const int t = threadIdx.x;
    if (t < 64) {
        const int c = t & 7;                    // component
        double p = 0.0;
        for (int sidx = t >> 3; sidx < nblk; sidx += 8)
            p += acc[sidx * 8 + c];
        red[t] = p;
    }
    __syncthreads();
    if (t < 8) {
        double tot = 0.0;
        #pragma unroll
        for (int k = 0; k < 8; ++k) tot += red[t + 8 * k];
        tot_s[t] = tot;
    }
    __syncthreads();
    if (t < 4) {
        double invB = 1.0 / (double)B;
        double mu   = tot_s[t] * invB;
        double var  = tot_s[4 + t] * invB - mu * mu;
        mu_s[t] = (float)mu;
        sc_s[t] = (float)(1.0 / sqrt(var + 1e-5)) * gamma[t];
        bt_s[t] = beta[t];
    }
    __syncthreads();
    int idx = blockIdx.x * blockDim.x + t;
    if (idx < B) {
        float4* o4 = (float4*)out;
        float4 v = o4[idx];
        v.x = (v.x - mu_s[0]) * sc_s[0] + bt_s[0];
        v.y = (v.y - mu_s[1]) * sc_s[1] + bt_s[1];
        v.z = (v.z - mu_s[2]) * sc_s[2] + bt_s[2];
        v.w = (v.w - mu_s[3]) * sc_s[3] + bt_s[3];
        o4[idx] = v;
    }
}

extern "C" void kernel_launch(void* const* d_in, const int* in_sizes, int n_in,
                              void* d_out, int out_size, void* d_ws, size_t ws_size,
                              hipStream_t stream) {
    const float* x       = (const float*)d_in[0];
    const float* W       = (const float*)d_in[1];
    const float* b       = (const float*)d_in[2];
    const float* vparams = (const float*)d_in[3];
    const float* gamma   = (const float*)d_in[4];
    const float* beta    = (const float*)d_in[5];
    float* out = (float*)d_out;
    const int B = in_sizes[0] / IMG_F;

    double* acc = (double*)d_ws;

    int nsets_tot = (B + IMG_PER_SET - 1) / IMG_PER_SET;
    int nblk = NBLOCKS;
    if (nblk > nsets_tot) nblk = nsets_tot;
    int maxblk = (int)(ws_size / (8 * sizeof(double)));
    if (nblk > maxblk && maxblk > 0) nblk = maxblk;     // ws guard
    int nsets_blk = (nsets_tot + nblk - 1) / nblk;

    qfc_main<<<nblk, 256, 0, stream>>>(x, W, b, vparams, out, acc,
                                       B, nsets_tot, nblk, nsets_blk);

    int nblk2 = (B + 255) / 256;
    qfc_bn<<<nblk2, 256, 0, stream>>>(out, acc, gamma, beta, B, nblk);
}

// Round 3
// 287.143 us; speedup vs baseline: 1.0518x; 1.0518x over previous
//
#include <hip/hip_runtime.h>
#include <math.h>

// QFCModel: avgpool(6x6) -> linear(16->4) -> 4-qubit circuit -> <Z> -> batchnorm
//
// |psi> = U_var * |enc(f)>, U_var fixed 16x16 complex (from vparams).
// enc[j] = r_j * (-i)^popcount(j), r_j real product of cos/sin half-angles.
// Fold phase into U columns => y_i = sum_j U'[i][j] * r_j  (real multiplier).
// <Z_w> = Walsh coefficient m=1<<(3-w) of q_i = |y_i|^2 (16-lane shfl butterfly).
//
// R6: drop LDS image staging entirely (R5 post-mortem: compiler drains vmcnt
// before LDS reads -> no pipelining is possible at source level; overlap on
// this kernel comes from TLP). Each thread loads its own 6x6 pool window
// directly: 2 x dwordx4 per row (aligned 8-col window, 6 cols selected via
// one cndmask), 12 VMEM/thread, L1 absorbs line re-visits. LDS = 2KB (Uc
// only) -> occupancy VGPR-bound ~5 blocks/CU; single barrier after U'-build;
// loads issued first so the ~250cy U'-build hides their latency.
// Same HBM lines touched as staged version (~176 MB fetch).

#define IMG_PER_BLOCK 16
#define IMG_F 784            // floats per image (28*28)
#define ACC_SETS 64

__global__ __launch_bounds__(256, 4) void qfc_main(
    const float* __restrict__ x,
    const float* __restrict__ W,
    const float* __restrict__ bias,
    const float* __restrict__ vparams,
    float* __restrict__ out,
    double* __restrict__ acc,   // [ACC_SETS][8]: 4 sums, 4 sumsq (pre-zeroed)
    int B)
{
    __shared__ float2 Uc[256];                          // 2048 B
    __shared__ float  bsum[4], bsq[4];

    const int t   = threadIdx.x;
    const int blk = blockIdx.x;

    if (t < 4) { bsum[t] = 0.f; bsq[t] = 0.f; }

    // ---- thread -> (image g, pool cell (ci,cj)) ----
    const int g = t >> 4, cell = t & 15;
    const int ci = cell >> 2, cj = cell & 3;
    int img = blk * IMG_PER_BLOCK + g;
    const bool valid = (img < B);
    if (!valid) img = 0;                                // clamp loads, no store

    // ---- issue the 12 pooling loads FIRST (latency hidden by U'-build) ----
    // Window: 8 aligned cols starting at (6*cj)&~3 contain the 6 needed.
    //   cj=0: cols 0-7  need 0-5   (even: lo2 + mid4)
    //   cj=1: cols 4-11 need 6-11  (odd:  mid4 + hi2)
    //   cj=2: cols12-19 need 12-17 (even)
    //   cj=3: cols16-23 need 18-23 (odd)
    const float* ibase = x + (long)img * IMG_F + (ci * 6) * 28 + ((6 * cj) & ~3);
    float4 va[6], vb[6];
    #pragma unroll
    for (int r = 0; r < 6; ++r) {
        const float4* rp = (const float4*)(ibase + r * 28);   // 16B-aligned
        va[r] = rp[0];
        vb[r] = rp[1];
    }

    // ---- U'-build (overlaps load latency). t -> column j = t>>4, row i ----
    {
        const int j = t >> 4, i = t & 15;
        float ux = (i == j) ? 1.f : 0.f, uy = 0.f;
        for (int l = 0; l < 3; ++l) {
            for (int w = 0; w < 4; ++w) {
                const float* vp = vparams + (l * 4 + w) * 3;
                const int m = 8 >> w;       // wire w = state bit (3-w)
                float s, c;
                // RX: [c, -i s; -i s, c]
                __sincosf(0.5f * vp[0], &s, &c);
                {
                    float ox = __shfl_xor(ux, m);
                    float oy = __shfl_xor(uy, m);
                    float nx = c * ux + s * oy;
                    float ny = c * uy - s * ox;
                    ux = nx; uy = ny;
                }
                // RY: [c, -s; s, c]
                __sincosf(0.5f * vp[1], &s, &c);
                {
                    float ox = __shfl_xor(ux, m);
                    float oy = __shfl_xor(uy, m);
                    float sg = (i & m) ? s : -s;
                    ux = c * ux + sg * ox;
                    uy = c * uy + sg * oy;
                }
                // RZ: diag(e^{-it/2}, e^{it/2})
                __sincosf(0.5f * vp[2], &s, &c);
                {
                    float sg = (i & m) ? s : -s;
                    float nx = ux * c - sg * uy;
                    float ny = uy * c + sg * ux;
                    ux = nx; uy = ny;
                }
            }
            // CNOT chain: control bit (3-w), target bit (2-w)
            for (int w = 0; w < 3; ++w) {
                int mc = 8 >> w, mt = 4 >> w;
                float ox = __shfl_xor(ux, mt);
                float oy = __shfl_xor(uy, mt);
                if (i & mc) { ux = ox; uy = oy; }
            }
        }
        int pc = __popc(j) & 3;             // fold column phase (-i)^popcount(j)
        float px, py;
        if (pc == 0)      { px =  ux; py =  uy; }
        else if (pc == 1) { px =  uy; py = -ux; }
        else if (pc == 2) { px = -ux; py = -uy; }
        else              { px = -uy; py =  ux; }
        Uc[t] = make_float2(px, py);        // Uc[j*16+i] = U'[j][i]
    }
    __syncthreads();    // Uc + bsum zero visible to all waves

    // ---- pooling sum (register-only) ----
    float pv;
    {
        const bool odd = (cj & 1);
        float sum = 0.f;
        #pragma unroll
        for (int r = 0; r < 6; ++r) {
            float mid  = va[r].z + va[r].w + vb[r].x + vb[r].y;
            float ends = odd ? (vb[r].z + vb[r].w) : (va[r].x + va[r].y);
            sum += mid + ends;
        }
        pv = sum * (1.0f / 36.0f);
    }
    // pooled value for (g, cell=k) lives in wave lane (t&48)|k — no barrier

    // ---- per-sample circuit: thread t -> image g, row i ----
    {
        const int i = t & 15;
        float f0 = bias[0], f1 = bias[1], f2 = bias[2], f3 = bias[3];
        #pragma unroll
        for (int k = 0; k < 16; ++k) {
            float p = __shfl(pv, (t & 48) | k, 64);
            f0 += p * W[k * 4 + 0];
            f1 += p * W[k * 4 + 1];
            f2 += p * W[k * 4 + 2];
            f3 += p * W[k * 4 + 3];
        }
        float c0, s0, c1, s1, c2, s2, c3, s3;
        __sincosf(0.5f * f0, &s0, &c0);
        __sincosf(0.5f * f1, &s1, &c1);
        __sincosf(0.5f * f2, &s2, &c2);
        __sincosf(0.5f * f3, &s3, &c3);
        // r_j = AB[j>>2] * CD[j&3]; bit3=wire0 ... bit0=wire3
        float AB[4] = { c0 * c1, c0 * s1, s0 * c1, s0 * s1 };
        float CD[4] = { c2 * c3, c2 * s3, s2 * c3, s2 * s3 };
        float yx = 0.f, yy = 0.f;
        #pragma unroll
        for (int j = 0; j < 16; ++j) {
            float r = AB[j >> 2] * CD[j & 3];
            float2 u = Uc[j * 16 + i];
            yx += u.x * r;
            yy += u.y * r;
        }
        float q = yx * yx + yy * yy;
        // 16-lane Walsh-Hadamard butterfly
        #pragma unroll
        for (int d = 1; d <= 8; d <<= 1) {
            float o = __shfl_xor(q, d);
            q = (i & d) ? (o - q) : (o + q);
        }
        if ((i == 1 || i == 2 || i == 4 || i == 8) && valid) {
            int w = (i == 8) ? 0 : (i == 4) ? 1 : (i == 2) ? 2 : 3;
            out[img * 4 + w] = q;       // raw <Z_w>, normalized in kernel 2
            atomicAdd(&bsum[w], q);
            atomicAdd(&bsq[w],  q * q);
        }
    }
    __syncthreads();

    if (t < 4) {
        int s = blk & (ACC_SETS - 1);
        atomicAdd(&acc[s * 8 + t],     (double)bsum[t]);
        atomicAdd(&acc[s * 8 + 4 + t], (double)bsq[t]);
    }
}

__global__ __launch_bounds__(256) void qfc_bn(
    float* __restrict__ out,
    const double* __restrict__ acc,
    const float* __restrict__ gamma,
    const float* __restrict__ beta,
    int B)
{
    __shared__ double tot_s[8];
    __shared__ float  mu_s[4], sc_s[4], bt_s[4];
    const int t = threadIdx.x;
    if (t < 8) {
        double tot = 0.0;
        for (int s = 0; s < ACC_SETS; ++s) tot += acc[s * 8 + t];
        tot_s[t] = tot;
    }
    __syncthreads();
    if (t < 4) {
        double invB = 1.0 / (double)B;
        double mu   = tot_s[t] * invB;
        double var  = tot_s[4 + t] * invB - mu * mu;
        mu_s[t] = (float)mu;
        sc_s[t] = (float)(1.0 / sqrt(var + 1e-5)) * gamma[t];
        bt_s[t] = beta[t];
    }
    __syncthreads();
    int idx = blockIdx.x * blockDim.x + t;
    if (idx < B) {
        float4* o4 = (float4*)out;
        float4 v = o4[idx];
        v.x = (v.x - mu_s[0]) * sc_s[0] + bt_s[0];
        v.y = (v.y - mu_s[1]) * sc_s[1] + bt_s[1];
        v.z = (v.z - mu_s[2]) * sc_s[2] + bt_s[2];
        v.w = (v.w - mu_s[3]) * sc_s[3] + bt_s[3];
        o4[idx] = v;
    }
}

extern "C" void kernel_launch(void* const* d_in, const int* in_sizes, int n_in,
                              void* d_out, int out_size, void* d_ws, size_t ws_size,
                              hipStream_t stream) {
    const float* x       = (const float*)d_in[0];
    const float* W       = (const float*)d_in[1];
    const float* b       = (const float*)d_in[2];
    const float* vparams = (const float*)d_in[3];
    const float* gamma   = (const float*)d_in[4];
    const float* beta    = (const float*)d_in[5];
    float* out = (float*)d_out;
    const int B = in_sizes[0] / IMG_F;

    double* acc = (double*)d_ws;                        // 64*8 doubles = 4KB
    hipMemsetAsync(d_ws, 0, ACC_SETS * 8 * sizeof(double), stream);

    int nblk1 = (B + IMG_PER_BLOCK - 1) / IMG_PER_BLOCK;
    qfc_main<<<nblk1, 256, 0, stream>>>(x, W, b, vparams, out, acc, B);

    int nblk2 = (B + 255) / 256;
    qfc_bn<<<nblk2, 256, 0, stream>>>(out, acc, gamma, beta, B);
}